// Round 10
// baseline (366.538 us; speedup 1.0000x reference)
//
#include <hip/hip_runtime.h>

static constexpr int Lc = 512;
static constexpr int Bc = 256;
static constexpr int Tc = 128;
static constexpr int AS = 136;   // Abuf row stride (bf16): 272 B, 16B-aligned
static constexpr int FS = 132;   // fin row stride (f32)

typedef short bf16x8 __attribute__((ext_vector_type(8)));
typedef float f32x4  __attribute__((ext_vector_type(4)));

__device__ __forceinline__ unsigned short f2bf(float x) {   // RNE f32->bf16
  unsigned u = __float_as_uint(x);
  return (unsigned short)((u + 0x7FFFu + ((u >> 16) & 1u)) >> 16);
}
__device__ __forceinline__ float bf2f(unsigned short h) {
  return __uint_as_float(((unsigned)h) << 16);
}
__device__ __forceinline__ int expo_of(float x) {
  int e = (int)((__float_as_uint(x) >> 23) & 0xff) - 127;
  return min(max(e, -100), 100);
}

// 16 blocks x 512 threads. Block owns 16 batches; wave w owns j-tile 16w.
// Step t: D[b][j] = sum_k P[b][k] * E[k][j] via 4x mfma_f32_16x16x32_bf16;
// epilogue: *eEm, per-ROW power-of-2 rescale, bf16 write to LDS A-buffer.
// A/B frags share the same (lane,elem)->k map => permutation-safe; C/D map
// is the HW-verified col=lane&15, row=(lane>>4)*4+reg.
// Loop barrier drains lgkmcnt ONLY (R9-proven): em prefetches stay in flight.
__launch_bounds__(512, 1)
__global__ void crf_llh_kernel(const float* __restrict__ emis,
                               const int* __restrict__ tags,
                               const int* __restrict__ mask,
                               const float* __restrict__ startT,
                               const float* __restrict__ endT,
                               const float* __restrict__ trans,
                               float* __restrict__ partial)
{
  const int tid = threadIdx.x;
  const int w   = tid >> 6;    // wave 0..7
  const int l   = tid & 63;
  const int g   = l >> 4;      // k-group / row-group
  const int cc  = l & 15;      // col within tile (and A-row for ds_read)
  const int j0  = w * 16;
  const int b0  = blockIdx.x * 16;

  __shared__ __align__(16) unsigned short Abuf[2][16 * AS];
  __shared__ __align__(16) int expo_lds[2][16];
  __shared__ __align__(16) float fin[16 * FS];
  __shared__ __align__(16) int ksum_lds[16];
  __shared__ float m0_lds[16];
  __shared__ float score_lds[16];
  __shared__ float wredv[16][8];
  __shared__ float wredc[16][8];

  // ================= numerator (gold-path score) =================
  {
    const int bb = b0 + (tid & 15);
    float v = 0.f, cnt = 0.f;
    #pragma unroll 4
    for (int k = 0; k < 16; ++k) {
      const int t = (tid >> 4) + 32 * k;
      const float mf  = (float)mask[t * Bc + bb];
      const int tag_t = tags[t * Bc + bb];
      float e = emis[((size_t)t * Bc + bb) * Tc + tag_t] * mf;
      if (t >= 1) e += trans[tags[(t - 1) * Bc + bb] * Tc + tag_t] * mf;
      v += e; cnt += mf;
    }
    v   += __shfl_xor(v, 16);   v   += __shfl_xor(v, 32);
    cnt += __shfl_xor(cnt, 16); cnt += __shfl_xor(cnt, 32);
    if (l < 16) { wredv[l][w] = v; wredc[l][w] = cnt; }
    __syncthreads();
    if (tid < 16) {
      float sv = 0.f, sc = 0.f;
      #pragma unroll
      for (int q = 0; q < 8; ++q) { sv += wredv[tid][q]; sc += wredc[tid][q]; }
      const int bbb  = b0 + tid;
      const int last = (int)(sc + 0.5f) - 1;
      score_lds[tid] = sv + startT[tags[bbb]] + endT[tags[last * Bc + bbb]];
      expo_lds[0][tid] = 0;
    }
  }

  // ================= B fragments: E[k][j] = exp(trans[k][j]) =================
  bf16x8 Bf0, Bf1, Bf2, Bf3;
  #pragma unroll
  for (int e = 0; e < 8; ++e) {
    Bf0[e] = (short)f2bf(__expf(trans[(  0 + g * 8 + e) * Tc + j0 + cc]));
    Bf1[e] = (short)f2bf(__expf(trans[( 32 + g * 8 + e) * Tc + j0 + cc]));
    Bf2[e] = (short)f2bf(__expf(trans[( 64 + g * 8 + e) * Tc + j0 + cc]));
    Bf3[e] = (short)f2bf(__expf(trans[( 96 + g * 8 + e) * Tc + j0 + cc]));
  }
  const float eEnd = __expf(endT[j0 + cc]);

  // ================= init: per-row M0, P0 into Abuf[0] =================
  {
    const int row  = tid >> 5;
    const int col4 = (tid & 31) * 4;
    const float4 st4 = *(const float4*)&startT[col4];
    const float4 em4 = *(const float4*)&emis[(size_t)(b0 + row) * Tc + col4];
    const float lp0 = st4.x + em4.x, lp1 = st4.y + em4.y;
    const float lp2 = st4.z + em4.z, lp3 = st4.w + em4.w;
    float wm = fmaxf(fmaxf(lp0, lp1), fmaxf(lp2, lp3));
    #pragma unroll
    for (int o = 1; o < 32; o <<= 1) wm = fmaxf(wm, __shfl_xor(wm, o));
    if ((tid & 31) == 0) m0_lds[row] = wm;
    __syncthreads();
    const float M0r = m0_lds[row];
    uint2 pk;
    pk.x = (unsigned)f2bf(__expf(lp0 - M0r)) | ((unsigned)f2bf(__expf(lp1 - M0r)) << 16);
    pk.y = (unsigned)f2bf(__expf(lp2 - M0r)) | ((unsigned)f2bf(__expf(lp3 - M0r)) << 16);
    *(uint2*)&Abuf[0][row * AS + col4] = pk;
  }
  __syncthreads();

  // carried values for this lane's 4 (row, col) outputs
  float pP0 = bf2f(Abuf[0][(g * 4 + 0) * AS + j0 + cc]);
  float pP1 = bf2f(Abuf[0][(g * 4 + 1) * AS + j0 + cc]);
  float pP2 = bf2f(Abuf[0][(g * 4 + 2) * AS + j0 + cc]);
  float pP3 = bf2f(Abuf[0][(g * 4 + 3) * AS + j0 + cc]);

  // ================= em/mask prefetch pipeline, 3 deep =================
  const size_t strideT = (size_t)Bc * Tc;
  const size_t off0 = (size_t)(b0 + g * 4 + 0) * Tc + j0 + cc;
  const size_t off1 = off0 + Tc, off2 = off1 + Tc, off3 = off2 + Tc;

  float emA0 = emis[1 * strideT + off0], emA1 = emis[1 * strideT + off1],
        emA2 = emis[1 * strideT + off2], emA3 = emis[1 * strideT + off3];
  float emB0 = emis[2 * strideT + off0], emB1 = emis[2 * strideT + off1],
        emB2 = emis[2 * strideT + off2], emB3 = emis[2 * strideT + off3];
  float emC0 = emis[3 * strideT + off0], emC1 = emis[3 * strideT + off1],
        emC2 = emis[3 * strideT + off2], emC3 = emis[3 * strideT + off3];
  int4 mA = *(const int4*)(mask + 1 * Bc + b0 + g * 4);
  int4 mB = *(const int4*)(mask + 2 * Bc + b0 + g * 4);
  int4 mC = *(const int4*)(mask + 3 * Bc + b0 + g * 4);
  const float* emP = emis + 4 * strideT;
  const int*   mP  = mask + 4 * Bc + b0 + g * 4;

  // ================= forward recurrence =================
  int Ks0 = 0, Ks1 = 0, Ks2 = 0, Ks3 = 0;
  int buf = 0;
  for (int t = 1; t < Lc; ++t) {
    const int4 e4 = *(const int4*)&expo_lds[buf][g * 4];
    const unsigned short* Ab = &Abuf[buf][cc * AS + g * 8];
    const bf16x8 a0 = *(const bf16x8*)(Ab + 0);
    const bf16x8 a1 = *(const bf16x8*)(Ab + 32);
    const bf16x8 a2 = *(const bf16x8*)(Ab + 64);
    const bf16x8 a3 = *(const bf16x8*)(Ab + 96);

    f32x4 acc0 = {0.f, 0.f, 0.f, 0.f};
    f32x4 acc1 = {0.f, 0.f, 0.f, 0.f};
    acc0 = __builtin_amdgcn_mfma_f32_16x16x32_bf16(a0, Bf0, acc0, 0, 0, 0);
    acc1 = __builtin_amdgcn_mfma_f32_16x16x32_bf16(a1, Bf1, acc1, 0, 0, 0);
    acc0 = __builtin_amdgcn_mfma_f32_16x16x32_bf16(a2, Bf2, acc0, 0, 0, 0);
    acc1 = __builtin_amdgcn_mfma_f32_16x16x32_bf16(a3, Bf3, acc1, 0, 0, 0);

    const float eE0 = __expf(emA0), eE1 = __expf(emA1);
    const float eE2 = __expf(emA2), eE3 = __expf(emA3);

    // prefetch t+3 (stays in flight across the raw barrier)
    float emN0 = 0.f, emN1 = 0.f, emN2 = 0.f, emN3 = 0.f;
    int4 mN = {0, 0, 0, 0};
    if (t + 3 < Lc) {
      emN0 = emP[off0]; emN1 = emP[off1]; emN2 = emP[off2]; emN3 = emP[off3];
      mN = *(const int4*)mP;
      emP += strideT; mP += Bc;
    }

    const int nxt = buf ^ 1;
    {
      float pn = mA.x ? (acc0[0] + acc1[0]) * eE0 : pP0;
      pn *= __uint_as_float((unsigned)(127 - e4.x) << 23);
      Ks0 += e4.x; pP0 = pn;
      Abuf[nxt][(g * 4 + 0) * AS + j0 + cc] = f2bf(pn);
    }
    {
      float pn = mA.y ? (acc0[1] + acc1[1]) * eE1 : pP1;
      pn *= __uint_as_float((unsigned)(127 - e4.y) << 23);
      Ks1 += e4.y; pP1 = pn;
      Abuf[nxt][(g * 4 + 1) * AS + j0 + cc] = f2bf(pn);
    }
    {
      float pn = mA.z ? (acc0[2] + acc1[2]) * eE2 : pP2;
      pn *= __uint_as_float((unsigned)(127 - e4.z) << 23);
      Ks2 += e4.z; pP2 = pn;
      Abuf[nxt][(g * 4 + 2) * AS + j0 + cc] = f2bf(pn);
    }
    {
      float pn = mA.w ? (acc0[3] + acc1[3]) * eE3 : pP3;
      pn *= __uint_as_float((unsigned)(127 - e4.w) << 23);
      Ks3 += e4.w; pP3 = pn;
      Abuf[nxt][(g * 4 + 3) * AS + j0 + cc] = f2bf(pn);
    }

    // per-row rescale exponents from column 0 (wave 0, cc==0 lanes)
    if (w == 0 && cc == 0) {
      int4 ne;
      ne.x = expo_of(pP0); ne.y = expo_of(pP1);
      ne.z = expo_of(pP2); ne.w = expo_of(pP3);
      *(int4*)&expo_lds[nxt][g * 4] = ne;
    }

    emA0 = emB0; emA1 = emB1; emA2 = emB2; emA3 = emB3;
    emB0 = emC0; emB1 = emC1; emB2 = emC2; emB3 = emC3;
    emC0 = emN0; emC1 = emN1; emC2 = emN2; emC3 = emN3;
    mA = mB; mB = mC; mC = mN;

    asm volatile("s_waitcnt lgkmcnt(0)" ::: "memory");
    __builtin_amdgcn_s_barrier();
    asm volatile("" ::: "memory");
    buf = nxt;
  }

  // ================= final: per-row LSE =================
  fin[(g * 4 + 0) * FS + j0 + cc] = pP0 * eEnd;
  fin[(g * 4 + 1) * FS + j0 + cc] = pP1 * eEnd;
  fin[(g * 4 + 2) * FS + j0 + cc] = pP2 * eEnd;
  fin[(g * 4 + 3) * FS + j0 + cc] = pP3 * eEnd;
  if (w == 0 && cc == 0) {
    int4 kk; kk.x = Ks0; kk.y = Ks1; kk.z = Ks2; kk.w = Ks3;
    *(int4*)&ksum_lds[g * 4] = kk;
  }
  __syncthreads();
  {
    const int row  = tid >> 5;
    const int col4 = (tid & 31) * 4;
    const float4 f4 = *(const float4*)&fin[row * FS + col4];
    float ss = (f4.x + f4.y) + (f4.z + f4.w);
    #pragma unroll
    for (int o = 1; o < 32; o <<= 1) ss += __shfl_xor(ss, o);
    if ((tid & 31) == 0) {
      const float denom = m0_lds[row]
                        + (float)ksum_lds[row] * 0.69314718055994531f
                        + __logf(ss);
      partial[b0 + row] = score_lds[row] - denom;
    }
  }
}

// Deterministic final reduction of 256 per-batch llh values -> scalar.
__global__ void crf_reduce(const float* __restrict__ partial, float* __restrict__ out)
{
  const int tid = threadIdx.x;  // 256 threads
  float v = partial[tid];
  #pragma unroll
  for (int o = 1; o < 64; o <<= 1) v += __shfl_xor(v, o);
  __shared__ float ws[4];
  if ((tid & 63) == 0) ws[tid >> 6] = v;
  __syncthreads();
  if (tid == 0) out[0] = (ws[0] + ws[1]) + (ws[2] + ws[3]);
}

extern "C" void kernel_launch(void* const* d_in, const int* in_sizes, int n_in,
                              void* d_out, int out_size, void* d_ws, size_t ws_size,
                              hipStream_t stream)
{
  const float* emis   = (const float*)d_in[0];
  const int*   tags   = (const int*)d_in[1];
  const int*   mask   = (const int*)d_in[2];
  const float* startT = (const float*)d_in[3];
  const float* endT   = (const float*)d_in[4];
  const float* trans  = (const float*)d_in[5];

  float* partial = (float*)d_ws;  // 256 floats

  crf_llh_kernel<<<Bc / 16, 512, 0, stream>>>(emis, tags, mask, startT, endT, trans, partial);
  crf_reduce<<<1, Bc, 0, stream>>>(partial, (float*)d_out);
}

// Round 11
// 318.582 us; speedup vs baseline: 1.1505x; 1.1505x over previous
//
#include <hip/hip_runtime.h>

static constexpr int Lc = 512;
static constexpr int Bc = 256;
static constexpr int Tc = 128;

// DPP quad-permute add: combine the 4 h-slices (lanes of one quad), VALU-speed.
template <int CTRL>
__device__ __forceinline__ float quad_add(float x) {
  const int y = __builtin_amdgcn_update_dpp(0, __float_as_int(x), CTRL, 0xf, 0xf, true);
  return x + __int_as_float(y);
}

// TWO batches per block (batch-level ILP): 128 blocks x 512 threads.
// Thread tid: output tag j = tid>>2, slice h = tid&3 (32 i's), for BOTH
// batches bA = 2*blockIdx, bB = bA+1. E-slice (32 f32, VGPR-resident --
// R3/R9-proven shape) is SHARED between the two batches; while batch A's
// LDS-read/DPP chain stalls, batch B's FMAs issue. One barrier period
// advances both batches one step.
// Loop barrier = s_waitcnt lgkmcnt(0) + raw s_barrier (R9-proven): global
// em prefetches stay in flight across the barrier; depth 3 > HBM latency.
__launch_bounds__(512, 1)
__global__ void crf_llh_kernel(const float* __restrict__ emis,
                               const int* __restrict__ tags,
                               const int* __restrict__ mask,
                               const float* __restrict__ startT,
                               const float* __restrict__ endT,
                               const float* __restrict__ trans,
                               float* __restrict__ partial)
{
  const int bA   = blockIdx.x * 2;
  const int bB   = bA + 1;
  const int tid  = threadIdx.x;
  const int j    = tid >> 2;   // 0..127
  const int h    = tid & 3;    // 0..3
  const int wid  = tid >> 6;   // 0..7
  const int lane = tid & 63;
  const int seg  = (j >> 5) * 36 + (j & 31);   // padded p-slot

  __shared__ __align__(16) float p_lds[2][2][4 * 36];  // [buf][batch][slot]
  __shared__ int expo_lds[2][2];                       // [buf][batch]
  __shared__ float wred[4][8];

  // ---------------- phase 0: numerator (gold-path score), both batches ----
  float scoreA = 0.f, scoreB = 0.f;  // tid 0 only
  {
    const int t = tid;
    const float mfA  = (float)mask[t * Bc + bA];
    const float mfB  = (float)mask[t * Bc + bB];
    const int tagA = tags[t * Bc + bA];
    const int tagB = tags[t * Bc + bB];
    float vA = emis[((size_t)t * Bc + bA) * Tc + tagA] * mfA;
    float vB = emis[((size_t)t * Bc + bB) * Tc + tagB] * mfB;
    if (t >= 1) {
      vA += trans[tags[(t - 1) * Bc + bA] * Tc + tagA] * mfA;
      vB += trans[tags[(t - 1) * Bc + bB] * Tc + tagB] * mfB;
    }
    float cA = mfA, cB = mfB;
    #pragma unroll
    for (int o = 1; o < 64; o <<= 1) {
      vA += __shfl_xor(vA, o);  cA += __shfl_xor(cA, o);
      vB += __shfl_xor(vB, o);  cB += __shfl_xor(cB, o);
    }
    if (lane == 0) {
      wred[0][wid] = vA; wred[1][wid] = cA;
      wred[2][wid] = vB; wred[3][wid] = cB;
    }
    __syncthreads();
    if (tid == 0) {
      float svA = 0.f, scA = 0.f, svB = 0.f, scB = 0.f;
      #pragma unroll
      for (int q = 0; q < 8; ++q) {
        svA += wred[0][q]; scA += wred[1][q];
        svB += wred[2][q]; scB += wred[3][q];
      }
      const int lastA = (int)(scA + 0.5f) - 1;
      const int lastB = (int)(scB + 0.5f) - 1;
      scoreA = svA + startT[tags[bA]] + endT[tags[lastA * Bc + bA]];
      scoreB = svB + startT[tags[bB]] + endT[tags[lastB * Bc + bB]];
    }
    __syncthreads();
  }

  // ---------------- E-slice: 32 f32 VGPRs, shared by both batches ----------
  float Ecol[32];
  #pragma unroll
  for (int q = 0; q < 32; ++q)
    Ecol[q] = __expf(trans[(h * 32 + q) * Tc + j]);
  const float eEnd = __expf(endT[j]);

  // ---------------- init t = 0, both batches ----------------
  const size_t strideT = (size_t)Bc * Tc;
  const float* empA = emis + (size_t)bA * Tc + j;
  const float* empB = emis + (size_t)bB * Tc + j;
  const float st0 = startT[j];
  const float lp0A = st0 + empA[0];
  const float lp0B = st0 + empB[0];

  float wmA = lp0A, wmB = lp0B;
  #pragma unroll
  for (int o = 4; o < 64; o <<= 1) {
    wmA = fmaxf(wmA, __shfl_xor(wmA, o));
    wmB = fmaxf(wmB, __shfl_xor(wmB, o));
  }
  if (lane == 0) { wred[0][wid] = wmA; wred[1][wid] = wmB; }
  __syncthreads();
  float M0A = wred[0][0], M0B = wred[1][0];
  #pragma unroll
  for (int q = 1; q < 8; ++q) {
    M0A = fmaxf(M0A, wred[0][q]);
    M0B = fmaxf(M0B, wred[1][q]);
  }
  float pjA = __expf(lp0A - M0A);
  float pjB = __expf(lp0B - M0B);
  if (h == 0) {
    p_lds[0][0][seg] = pjA;
    p_lds[0][1][seg] = pjB;
  }
  if (tid == 0) { expo_lds[0][0] = 0; expo_lds[0][1] = 0; }

  // ---------------- em/mask prefetch pipelines, 3 deep, both batches -------
  float emA0 = empA[1 * strideT], emA1 = empA[2 * strideT], emA2 = empA[3 * strideT];
  float emB0 = empB[1 * strideT], emB1 = empB[2 * strideT], emB2 = empB[3 * strideT];
  int   mA0  = mask[1 * Bc + bA], mA1 = mask[2 * Bc + bA], mA2 = mask[3 * Bc + bA];
  int   mB0  = mask[1 * Bc + bB], mB1 = mask[2 * Bc + bB], mB2 = mask[3 * Bc + bB];
  const float* empA3 = empA + 4 * strideT;
  const float* empB3 = empB + 4 * strideT;
  const int*   mpA3  = mask + 4 * Bc + bA;
  const int*   mpB3  = mask + 4 * Bc + bB;

  __syncthreads();   // p_lds[0], expo_lds[0] ready

  // ---------------- forward recurrence: 1 barrier advances both ------------
  int KsA = 0, KsB = 0;
  int buf = 0;
  #pragma unroll 2
  for (int t = 1; t < Lc; ++t) {
    const int e0A = expo_lds[buf][0];
    const int e0B = expo_lds[buf][1];

    // two independent GEMV slices (ILP: B's FMAs fill A's stalls)
    const float4* pvA = (const float4*)&p_lds[buf][0][h * 36];
    const float4* pvB = (const float4*)&p_lds[buf][1][h * 36];
    float a0 = 0.f, a1 = 0.f, a2 = 0.f, a3 = 0.f;
    float b0 = 0.f, b1 = 0.f, b2 = 0.f, b3 = 0.f;
    #pragma unroll
    for (int q = 0; q < 8; ++q) {
      const float4 pa = pvA[q];
      const float4 pb = pvB[q];
      a0 = fmaf(pa.x, Ecol[4 * q + 0], a0);
      b0 = fmaf(pb.x, Ecol[4 * q + 0], b0);
      a1 = fmaf(pa.y, Ecol[4 * q + 1], a1);
      b1 = fmaf(pb.y, Ecol[4 * q + 1], b1);
      a2 = fmaf(pa.z, Ecol[4 * q + 2], a2);
      b2 = fmaf(pb.z, Ecol[4 * q + 2], b2);
      a3 = fmaf(pa.w, Ecol[4 * q + 3], a3);
      b3 = fmaf(pb.w, Ecol[4 * q + 3], b3);
    }
    float sA = (a0 + a1) + (a2 + a3);
    float sB = (b0 + b1) + (b2 + b3);
    sA = quad_add<0xB1>(sA);
    sB = quad_add<0xB1>(sB);
    sA = quad_add<0x4E>(sA);
    sB = quad_add<0x4E>(sB);

    const float eEmA = __expf(emA0);
    const float eEmB = __expf(emB0);

    // prefetch t+3 (stays in flight across the raw barrier)
    float emNA = 0.f, emNB = 0.f; int mNA = 0, mNB = 0;
    if (t + 3 < Lc) {
      emNA = empA3[0];  emNB = empB3[0];
      mNA  = mpA3[0];   mNB  = mpB3[0];
      empA3 += strideT; empB3 += strideT;
      mpA3  += Bc;      mpB3  += Bc;
    }

    const float rA = __uint_as_float((unsigned)(127 - e0A) << 23);
    const float rB = __uint_as_float((unsigned)(127 - e0B) << 23);
    const float pnA = (mA0 ? sA * eEmA : pjA) * rA;
    const float pnB = (mB0 ? sB * eEmB : pjB) * rB;
    KsA += e0A;  KsB += e0B;
    pjA = pnA;   pjB = pnB;

    const int nxt = buf ^ 1;
    if (h == 0) {
      p_lds[nxt][0][seg] = pnA;
      p_lds[nxt][1][seg] = pnB;
    }
    if (tid == 0) {
      int eA = (int)((__float_as_uint(pnA) >> 23) & 0xff) - 127;
      int eB = (int)((__float_as_uint(pnB) >> 23) & 0xff) - 127;
      expo_lds[nxt][0] = min(max(eA, -100), 100);
      expo_lds[nxt][1] = min(max(eB, -100), 100);
    }

    // shift prefetch pipelines
    emA0 = emA1; emA1 = emA2; emA2 = emNA;
    emB0 = emB1; emB1 = emB2; emB2 = emNB;
    mA0  = mA1;  mA1  = mA2;  mA2  = mNA;
    mB0  = mB1;  mB1  = mB2;  mB2  = mNB;

    // raw barrier: drain LDS only; global loads remain outstanding
    asm volatile("s_waitcnt lgkmcnt(0)" ::: "memory");
    __builtin_amdgcn_s_barrier();
    asm volatile("" ::: "memory");

    buf = nxt;
  }

  // ---------------- final: denom = M0 + Ks*ln2 + log(sum p * e^end) --------
  float cA = (h == 0) ? pjA * eEnd : 0.f;
  float cB = (h == 0) ? pjB * eEnd : 0.f;
  #pragma unroll
  for (int o = 1; o < 64; o <<= 1) {
    cA += __shfl_xor(cA, o);
    cB += __shfl_xor(cB, o);
  }
  if (lane == 0) { wred[0][wid] = cA; wred[1][wid] = cB; }
  __syncthreads();
  if (tid == 0) {
    float ssA = 0.f, ssB = 0.f;
    #pragma unroll
    for (int q = 0; q < 8; ++q) { ssA += wred[0][q]; ssB += wred[1][q]; }
    const float denomA = M0A + (float)KsA * 0.69314718055994531f + __logf(ssA);
    const float denomB = M0B + (float)KsB * 0.69314718055994531f + __logf(ssB);
    partial[bA] = scoreA - denomA;
    partial[bB] = scoreB - denomB;
  }
}

// Deterministic final reduction of 256 per-batch llh values -> scalar.
__global__ void crf_reduce(const float* __restrict__ partial, float* __restrict__ out)
{
  const int tid = threadIdx.x;  // 256 threads
  float v = partial[tid];
  #pragma unroll
  for (int o = 1; o < 64; o <<= 1) v += __shfl_xor(v, o);
  __shared__ float ws[4];
  if ((tid & 63) == 0) ws[tid >> 6] = v;
  __syncthreads();
  if (tid == 0) out[0] = (ws[0] + ws[1]) + (ws[2] + ws[3]);
}

extern "C" void kernel_launch(void* const* d_in, const int* in_sizes, int n_in,
                              void* d_out, int out_size, void* d_ws, size_t ws_size,
                              hipStream_t stream)
{
  const float* emis   = (const float*)d_in[0];
  const int*   tags   = (const int*)d_in[1];
  const int*   mask   = (const int*)d_in[2];
  const float* startT = (const float*)d_in[3];
  const float* endT   = (const float*)d_in[4];
  const float* trans  = (const float*)d_in[5];

  float* partial = (float*)d_ws;  // 256 floats

  crf_llh_kernel<<<Bc / 2, 512, 0, stream>>>(emis, tags, mask, startT, endT, trans, partial);
  crf_reduce<<<1, Bc, 0, stream>>>(partial, (float*)d_out);
}

// Round 12
// 159.700 us; speedup vs baseline: 2.2952x; 1.9949x over previous
//
#include <hip/hip_runtime.h>

static constexpr int Lc = 512;
static constexpr int Bc = 256;
static constexpr int Tc = 128;

typedef _Float16 half2_t  __attribute__((ext_vector_type(2)));
typedef __fp16   fp16x2_t __attribute__((ext_vector_type(2)));

__device__ __forceinline__ float fdot2(half2_t a, half2_t b, float c) {
  return __builtin_amdgcn_fdot2(a, b, c, false);   // v_dot2_f32_f16
}
__device__ __forceinline__ unsigned pack_h2(float a, float b) {
  union { fp16x2_t h; unsigned u; } cv;
  cv.h = __builtin_amdgcn_cvt_pkrtz(a, b);         // v_cvt_pkrtz_f16_f32
  return cv.u;
}
__device__ __forceinline__ half2_t as_h2(unsigned u) {
  union { unsigned u; half2_t h; } cv;
  cv.u = u;
  return cv.h;
}
// quad_perm [1,0,3,2]: combine lane pairs (h=0 <-> h=1), VALU-speed.
__device__ __forceinline__ float pair_add(float x) {
  const int y = __builtin_amdgcn_update_dpp(0, __float_as_int(x), 0xB1, 0xf, 0xf, true);
  return x + __int_as_float(y);
}
// quad_perm [2,3,0,1]: lane 4q fetches lane 4q+2's value (j=2q+1's pn).
__device__ __forceinline__ float quad_fetch2(float x) {
  const int y = __builtin_amdgcn_update_dpp(0, __float_as_int(x), 0x4E, 0xf, 0xf, true);
  return __int_as_float(y);
}

// One block per batch (256 blocks). 256 threads = 4 waves (1/SIMD).
// Thread tid: j = tid>>1, i-half h = tid&1 (64 i's as 32 packed f16x2 in
// VGPRs -- the 32-reg array size this allocator provably keeps resident).
// p is f16x2-packed in LDS (64 u32): 8 ds_read_b128/thread, 32 dot2.
// Per-step rescale by 2^-e0 (exponent of p[j=0], block-uniform, exact).
// Loop barrier = lgkmcnt(0) + raw s_barrier (R9-proven): em prefetches stay
// in flight across barriers; depth 3 > HBM latency.
__launch_bounds__(256, 1)
__global__ void crf_llh_kernel(const float* __restrict__ emis,
                               const int* __restrict__ tags,
                               const int* __restrict__ mask,
                               const float* __restrict__ startT,
                               const float* __restrict__ endT,
                               const float* __restrict__ trans,
                               float* __restrict__ partial)
{
  const int b    = blockIdx.x;
  const int tid  = threadIdx.x;
  const int j    = tid >> 1;   // 0..127
  const int h    = tid & 1;    // i-half
  const int wid  = tid >> 6;   // wave 0..3
  const int lane = tid & 63;

  __shared__ __align__(16) unsigned p_lds[2][64];   // packed f16x2
  __shared__ int expo_lds[2];
  __shared__ float wredA[4];
  __shared__ float wredB[4];

  // ---------------- phase 0: numerator (gold-path score) ----------------
  float score = 0.0f;  // tid 0 only
  {
    float v = 0.f, c = 0.f;
    #pragma unroll
    for (int s2 = 0; s2 < 2; ++s2) {
      const int t     = tid + s2 * 256;
      const float mf  = (float)mask[t * Bc + b];
      const int tag_t = tags[t * Bc + b];
      float e = emis[((size_t)t * Bc + b) * Tc + tag_t] * mf;
      if (t >= 1) e += trans[tags[(t - 1) * Bc + b] * Tc + tag_t] * mf;
      v += e; c += mf;
    }
    #pragma unroll
    for (int o = 1; o < 64; o <<= 1) {
      v += __shfl_xor(v, o);
      c += __shfl_xor(c, o);
    }
    if (lane == 0) { wredA[wid] = v; wredB[wid] = c; }
    __syncthreads();
    if (tid == 0) {
      const float sv = (wredA[0] + wredA[1]) + (wredA[2] + wredA[3]);
      const float sc = (wredB[0] + wredB[1]) + (wredB[2] + wredB[3]);
      const int last_idx = (int)(sc + 0.5f) - 1;
      score = sv + startT[tags[b]] + endT[tags[last_idx * Bc + b]];
    }
    __syncthreads();
  }

  // -------- E-half-column, f16x2-packed along i: 32 u32 VGPRs --------
  unsigned Eu[32];
  #pragma unroll
  for (int q = 0; q < 32; ++q) {
    const float e0 = __expf(trans[(h * 64 + 2 * q)     * Tc + j]);
    const float e1 = __expf(trans[(h * 64 + 2 * q + 1) * Tc + j]);
    Eu[q] = pack_h2(e0, e1);
  }
  const float eEnd = __expf(endT[j]);

  // ---------------- init t = 0 ----------------
  const size_t strideT = (size_t)Bc * Tc;
  const float* emp = emis + (size_t)b * Tc + j;   // &em[0,b,j]
  const float lp0 = startT[j] + emp[0];

  float wm = lp0;
  #pragma unroll
  for (int o = 1; o < 64; o <<= 1) wm = fmaxf(wm, __shfl_xor(wm, o));
  if (lane == 0) wredA[wid] = wm;
  __syncthreads();
  const float M0 = fmaxf(fmaxf(wredA[0], wredA[1]), fmaxf(wredA[2], wredA[3]));

  float pj = __expf(lp0 - M0);                    // block max = 1 exactly
  {
    const float partner = quad_fetch2(pj);        // pn[j=2q+1] -> lane 4q
    const unsigned pk = pack_h2(pj, partner);
    if ((tid & 3) == 0) p_lds[0][tid >> 2] = pk;
    if (tid == 0) expo_lds[0] = 0;
  }

  // ---------------- em/mask prefetch pipeline, 3 deep ----------------
  float emR0 = emp[1 * strideT];
  float emR1 = emp[2 * strideT];
  float emR2 = emp[3 * strideT];
  int   mR0  = mask[1 * Bc + b];
  int   mR1  = mask[2 * Bc + b];
  int   mR2  = mask[3 * Bc + b];
  const float* emp3 = emp + 4 * strideT;
  const int*   mp3  = mask + 4 * Bc + b;

  __syncthreads();   // p_lds[0], expo_lds[0] ready

  // ---------------- forward recurrence ----------------
  int Ksum = 0;
  int buf  = 0;
  #pragma unroll 2
  for (int t = 1; t < Lc; ++t) {
    const int e0 = expo_lds[buf];

    // own i-half of p: 8x ds_read_b128, 2 broadcast addr groups (free)
    const uint4* pv = (const uint4*)&p_lds[buf][h * 32];
    float a0 = 0.f, a1 = 0.f, a2 = 0.f, a3 = 0.f;
    float a4 = 0.f, a5 = 0.f, a6 = 0.f, a7 = 0.f;
    #pragma unroll
    for (int q = 0; q < 8; ++q) {
      const uint4 pq = pv[q];
      if (q & 1) {
        a4 = fdot2(as_h2(pq.x), as_h2(Eu[q * 4 + 0]), a4);
        a5 = fdot2(as_h2(pq.y), as_h2(Eu[q * 4 + 1]), a5);
        a6 = fdot2(as_h2(pq.z), as_h2(Eu[q * 4 + 2]), a6);
        a7 = fdot2(as_h2(pq.w), as_h2(Eu[q * 4 + 3]), a7);
      } else {
        a0 = fdot2(as_h2(pq.x), as_h2(Eu[q * 4 + 0]), a0);
        a1 = fdot2(as_h2(pq.y), as_h2(Eu[q * 4 + 1]), a1);
        a2 = fdot2(as_h2(pq.z), as_h2(Eu[q * 4 + 2]), a2);
        a3 = fdot2(as_h2(pq.w), as_h2(Eu[q * 4 + 3]), a3);
      }
    }
    float s = ((a0 + a1) + (a2 + a3)) + ((a4 + a5) + (a6 + a7));
    s = pair_add(s);   // combine the two i-halves (lanes 2m <-> 2m+1)

    const float eEm = __expf(emR0);

    // prefetch t+3: stays in flight across the raw barrier
    float emNew = 0.f; int mNew = 0;
    if (t + 3 < Lc) {
      emNew = emp3[0];
      mNew  = mp3[0];
      emp3 += strideT;
      mp3  += Bc;
    }

    const float r  = __uint_as_float((unsigned)(127 - e0) << 23);  // 2^-e0
    const float pn = (mR0 ? s * eEm : pj) * r;
    Ksum += e0;
    pj = pn;

    const int nxt = buf ^ 1;
    const float partner = quad_fetch2(pn);
    const unsigned pk = pack_h2(pn, partner);
    if ((tid & 3) == 0) p_lds[nxt][tid >> 2] = pk;
    if (tid == 0) {
      int e = (int)((__float_as_uint(pn) >> 23) & 0xff) - 127;
      expo_lds[nxt] = min(max(e, -100), 100);
    }

    emR0 = emR1; emR1 = emR2; emR2 = emNew;
    mR0  = mR1;  mR1  = mR2;  mR2  = mNew;

    // raw barrier: drain LDS only; global loads remain outstanding
    asm volatile("s_waitcnt lgkmcnt(0)" ::: "memory");
    __builtin_amdgcn_s_barrier();
    asm volatile("" ::: "memory");

    buf = nxt;
  }

  // ---------------- final: denom = M0 + Ksum*ln2 + log(sum p*e^end) ----
  float contrib = (h == 0) ? pj * eEnd : 0.f;
  #pragma unroll
  for (int o = 1; o < 64; o <<= 1) contrib += __shfl_xor(contrib, o);
  if (lane == 0) wredA[wid] = contrib;
  __syncthreads();
  if (tid == 0) {
    const float ssum = (wredA[0] + wredA[1]) + (wredA[2] + wredA[3]);
    const float denom = M0 + (float)Ksum * 0.69314718055994531f + __logf(ssum);
    partial[b] = score - denom;
  }
}

// Deterministic final reduction of 256 per-batch llh values -> scalar.
__global__ void crf_reduce(const float* __restrict__ partial, float* __restrict__ out)
{
  const int tid = threadIdx.x;  // 256 threads
  float v = partial[tid];
  #pragma unroll
  for (int o = 1; o < 64; o <<= 1) v += __shfl_xor(v, o);
  __shared__ float ws[4];
  if ((tid & 63) == 0) ws[tid >> 6] = v;
  __syncthreads();
  if (tid == 0) out[0] = (ws[0] + ws[1]) + (ws[2] + ws[3]);
}

extern "C" void kernel_launch(void* const* d_in, const int* in_sizes, int n_in,
                              void* d_out, int out_size, void* d_ws, size_t ws_size,
                              hipStream_t stream)
{
  const float* emis   = (const float*)d_in[0];
  const int*   tags   = (const int*)d_in[1];
  const int*   mask   = (const int*)d_in[2];
  const float* startT = (const float*)d_in[3];
  const float* endT   = (const float*)d_in[4];
  const float* trans  = (const float*)d_in[5];

  float* partial = (float*)d_ws;  // 256 floats

  crf_llh_kernel<<<Bc, 256, 0, stream>>>(emis, tags, mask, startT, endT, trans, partial);
  crf_reduce<<<1, Bc, 0, stream>>>(partial, (float*)d_out);
}

// Round 13
// 122.107 us; speedup vs baseline: 3.0018x; 1.3079x over previous
//
#include <hip/hip_runtime.h>

static constexpr int Lc = 512;
static constexpr int Bc = 256;
static constexpr int Tc = 128;

typedef _Float16 half2_t  __attribute__((ext_vector_type(2)));
typedef __fp16   fp16x2_t __attribute__((ext_vector_type(2)));

__device__ __forceinline__ float fdot2(half2_t a, half2_t b, float c) {
  return __builtin_amdgcn_fdot2(a, b, c, false);   // v_dot2_f32_f16
}
__device__ __forceinline__ unsigned pack_h2(float a, float b) {
  union { fp16x2_t h; unsigned u; } cv;
  cv.h = __builtin_amdgcn_cvt_pkrtz(a, b);         // v_cvt_pkrtz_f16_f32
  return cv.u;
}
__device__ __forceinline__ half2_t as_h2(unsigned u) {
  union { unsigned u; half2_t h; } cv;
  cv.u = u;
  return cv.h;
}
// quad_perm [1,0,3,2]: combine lane pairs (h=0 <-> h=1).
__device__ __forceinline__ float pair_add(float x) {
  const int y = __builtin_amdgcn_update_dpp(0, __float_as_int(x), 0xB1, 0xf, 0xf, true);
  return x + __int_as_float(y);
}
// quad_perm [2,3,0,1]: lane 4m fetches lane 4m+2's value.
__device__ __forceinline__ float quad_fetch2(float x) {
  const int y = __builtin_amdgcn_update_dpp(0, __float_as_int(x), 0x4E, 0xf, 0xf, true);
  return __int_as_float(y);
}

// Meet-in-the-middle CRF: denom = end^T (S_511...S_1) p_0 is bilinear, so
// forward (p_255, 255 steps) and backward (q_255 = S_256^T..S_511^T end,
// 256 steps) chains run CONCURRENTLY in separate blocks -- the sequential
// wall-clock chain halves vs R12. Step machinery is R12's proven f16-dot2
// GEMV (256 thr, j|i = tid>>1, h = tid&1, 32 packed f16x2 E-regs), raw
// lgkmcnt-only barrier, power-of-2 rescale. Backward applies eEm on the
// writer side (u = eEm .* q) and reads E row-wise (transposed GEMV).
__launch_bounds__(256, 1)
__global__ void crf_llh_kernel(const float* __restrict__ emis,
                               const int* __restrict__ tags,
                               const int* __restrict__ mask,
                               const float* __restrict__ startT,
                               const float* __restrict__ endT,
                               const float* __restrict__ trans,
                               float* __restrict__ pbuf,    // [256][128]
                               float* __restrict__ qbuf,    // [256][128]
                               float* __restrict__ meta)    // [256][4] score,M0,Kf,Kb
{
  const int bid = blockIdx.x;
  const bool fwd = bid < Bc;
  const int b    = fwd ? bid : bid - Bc;
  const int tid  = threadIdx.x;
  const int j    = tid >> 1;   // fwd: out col j; bwd: out row i
  const int h    = tid & 1;    // half of the 128-reduction
  const int wid  = tid >> 6;
  const int lane = tid & 63;

  __shared__ __align__(16) unsigned p_lds[2][64];   // packed f16x2
  __shared__ int expo_lds[2];
  __shared__ float wredA[4];
  __shared__ float wredB[4];

  const size_t strideT = (size_t)Bc * Tc;
  const float* emp = emis + (size_t)b * Tc + j;

  if (fwd) {
    // ------------- phase 0: numerator (gold-path score) -------------
    float score = 0.0f;  // tid 0 only
    {
      float v = 0.f, c = 0.f;
      #pragma unroll
      for (int s2 = 0; s2 < 2; ++s2) {
        const int t     = tid + s2 * 256;
        const float mf  = (float)mask[t * Bc + b];
        const int tag_t = tags[t * Bc + b];
        float e = emis[((size_t)t * Bc + b) * Tc + tag_t] * mf;
        if (t >= 1) e += trans[tags[(t - 1) * Bc + b] * Tc + tag_t] * mf;
        v += e; c += mf;
      }
      #pragma unroll
      for (int o = 1; o < 64; o <<= 1) {
        v += __shfl_xor(v, o);
        c += __shfl_xor(c, o);
      }
      if (lane == 0) { wredA[wid] = v; wredB[wid] = c; }
      __syncthreads();
      if (tid == 0) {
        const float sv = (wredA[0] + wredA[1]) + (wredA[2] + wredA[3]);
        const float sc = (wredB[0] + wredB[1]) + (wredB[2] + wredB[3]);
        const int last_idx = (int)(sc + 0.5f) - 1;
        score = sv + startT[tags[b]] + endT[tags[last_idx * Bc + b]];
      }
      __syncthreads();
    }

    // E column-slice, f16x2-packed along i: Eu[k] = (E[h*64+2k][j], E[..+1][j])
    unsigned Eu[32];
    #pragma unroll
    for (int q = 0; q < 32; ++q) {
      const float e0 = __expf(trans[(h * 64 + 2 * q)     * Tc + j]);
      const float e1 = __expf(trans[(h * 64 + 2 * q + 1) * Tc + j]);
      Eu[q] = pack_h2(e0, e1);
    }

    // init t = 0
    const float lp0 = startT[j] + emp[0];
    float wm = lp0;
    #pragma unroll
    for (int o = 1; o < 64; o <<= 1) wm = fmaxf(wm, __shfl_xor(wm, o));
    if (lane == 0) wredA[wid] = wm;
    __syncthreads();
    const float M0 = fmaxf(fmaxf(wredA[0], wredA[1]), fmaxf(wredA[2], wredA[3]));

    float pj = __expf(lp0 - M0);
    {
      const float partner = quad_fetch2(pj);
      if ((tid & 3) == 0) p_lds[0][tid >> 2] = pack_h2(pj, partner);
      if (tid == 0) expo_lds[0] = 0;
    }

    float emR0 = emp[1 * strideT], emR1 = emp[2 * strideT], emR2 = emp[3 * strideT];
    int   mR0  = mask[1 * Bc + b], mR1 = mask[2 * Bc + b], mR2 = mask[3 * Bc + b];
    const float* emp3 = emp + 4 * strideT;
    const int*   mp3  = mask + 4 * Bc + b;
    __syncthreads();

    int Ksum = 0, buf = 0;
    #pragma unroll 2
    for (int t = 1; t <= 255; ++t) {
      const int e0 = expo_lds[buf];
      const uint4* pv = (const uint4*)&p_lds[buf][h * 32];
      float a0 = 0.f, a1 = 0.f, a2 = 0.f, a3 = 0.f;
      float a4 = 0.f, a5 = 0.f, a6 = 0.f, a7 = 0.f;
      #pragma unroll
      for (int q = 0; q < 8; ++q) {
        const uint4 pq = pv[q];
        if (q & 1) {
          a4 = fdot2(as_h2(pq.x), as_h2(Eu[q * 4 + 0]), a4);
          a5 = fdot2(as_h2(pq.y), as_h2(Eu[q * 4 + 1]), a5);
          a6 = fdot2(as_h2(pq.z), as_h2(Eu[q * 4 + 2]), a6);
          a7 = fdot2(as_h2(pq.w), as_h2(Eu[q * 4 + 3]), a7);
        } else {
          a0 = fdot2(as_h2(pq.x), as_h2(Eu[q * 4 + 0]), a0);
          a1 = fdot2(as_h2(pq.y), as_h2(Eu[q * 4 + 1]), a1);
          a2 = fdot2(as_h2(pq.z), as_h2(Eu[q * 4 + 2]), a2);
          a3 = fdot2(as_h2(pq.w), as_h2(Eu[q * 4 + 3]), a3);
        }
      }
      float s = ((a0 + a1) + (a2 + a3)) + ((a4 + a5) + (a6 + a7));
      s = pair_add(s);

      const float eEm = __expf(emR0);
      const float emNew = emp3[0];           // t+3 <= 258 < 512: always valid
      const int   mNew  = mp3[0];
      emp3 += strideT; mp3 += Bc;

      const float r  = __uint_as_float((unsigned)(127 - e0) << 23);
      const float pn = (mR0 ? s * eEm : pj) * r;
      Ksum += e0;
      pj = pn;

      const int nxt = buf ^ 1;
      const float partner = quad_fetch2(pn);
      if ((tid & 3) == 0) p_lds[nxt][tid >> 2] = pack_h2(pn, partner);
      if (tid == 0) {
        int e = (int)((__float_as_uint(pn) >> 23) & 0xff) - 127;
        expo_lds[nxt] = min(max(e, -100), 100);
      }

      emR0 = emR1; emR1 = emR2; emR2 = emNew;
      mR0  = mR1;  mR1  = mR2;  mR2  = mNew;

      asm volatile("s_waitcnt lgkmcnt(0)" ::: "memory");
      __builtin_amdgcn_s_barrier();
      asm volatile("" ::: "memory");
      buf = nxt;
    }

    // write p_255 + meta
    if (h == 0) pbuf[b * Tc + j] = pj;
    if (tid == 0) {
      meta[4 * b + 0] = score;
      meta[4 * b + 1] = M0;
      meta[4 * b + 2] = (float)Ksum;
    }
  } else {
    // ================= BACKWARD: q_255 = S_256^T ... S_511^T end_exp =======
    // E row-slice: Eu[k] = (E[i][h*64+2k], E[i][h*64+2k+1]), i = j (tid>>1)
    unsigned Eu[32];
    #pragma unroll
    for (int q = 0; q < 32; ++q) {
      const float2 tr2 = *(const float2*)&trans[j * Tc + h * 64 + 2 * q];
      Eu[q] = pack_h2(__expf(tr2.x), __expf(tr2.y));
    }

    // init: q_511 = exp(end); u_511 = eEm_511 .* q_511
    float qi = __expf(endT[j]);
    {
      const float u = qi * __expf(emp[511 * strideT]);
      const float partner = quad_fetch2(u);
      if ((tid & 3) == 0) p_lds[0][tid >> 2] = pack_h2(u, partner);
      if (tid == 0) expo_lds[0] = 0;
    }

    // mask stream: m[511], m[510], m[509]; em stream (for u at t-1):
    // em[510], em[509], em[508]
    int   mR0 = mask[511 * Bc + b], mR1 = mask[510 * Bc + b], mR2 = mask[509 * Bc + b];
    float emR0 = emp[510 * strideT], emR1 = emp[509 * strideT], emR2 = emp[508 * strideT];
    const float* emp3 = emp + 507 * strideT;   // em[507 - k]
    const int*   mp3  = mask + 508 * Bc + b;   // m[508 - k]
    __syncthreads();

    int Ksum = 0, buf = 0;
    #pragma unroll 2
    for (int k = 0; k < 256; ++k) {            // t = 511 - k
      const int e0 = expo_lds[buf];
      const uint4* pv = (const uint4*)&p_lds[buf][h * 32];
      float a0 = 0.f, a1 = 0.f, a2 = 0.f, a3 = 0.f;
      float a4 = 0.f, a5 = 0.f, a6 = 0.f, a7 = 0.f;
      #pragma unroll
      for (int q = 0; q < 8; ++q) {
        const uint4 pq = pv[q];
        if (q & 1) {
          a4 = fdot2(as_h2(pq.x), as_h2(Eu[q * 4 + 0]), a4);
          a5 = fdot2(as_h2(pq.y), as_h2(Eu[q * 4 + 1]), a5);
          a6 = fdot2(as_h2(pq.z), as_h2(Eu[q * 4 + 2]), a6);
          a7 = fdot2(as_h2(pq.w), as_h2(Eu[q * 4 + 3]), a7);
        } else {
          a0 = fdot2(as_h2(pq.x), as_h2(Eu[q * 4 + 0]), a0);
          a1 = fdot2(as_h2(pq.y), as_h2(Eu[q * 4 + 1]), a1);
          a2 = fdot2(as_h2(pq.z), as_h2(Eu[q * 4 + 2]), a2);
          a3 = fdot2(as_h2(pq.w), as_h2(Eu[q * 4 + 3]), a3);
        }
      }
      float s = ((a0 + a1) + (a2 + a3)) + ((a4 + a5) + (a6 + a7));
      s = pair_add(s);

      // loads always in-bounds: em[507-k] >= em[252], m[508-k] >= m[253]
      const float emNew = emp3[0];
      const int   mNew  = mp3[0];
      emp3 -= strideT; mp3 -= Bc;

      const float r  = __uint_as_float((unsigned)(127 - e0) << 23);
      const float pn = (mR0 ? s : qi) * r;     // q_{t-1}
      Ksum += e0;
      qi = pn;

      const int nxt = buf ^ 1;
      const float u = pn * __expf(emR0);       // u_{t-1} = eEm_{t-1} * q_{t-1}
      const float partner = quad_fetch2(u);
      if ((tid & 3) == 0) p_lds[nxt][tid >> 2] = pack_h2(u, partner);
      if (tid == 0) {
        int e = (int)((__float_as_uint(pn) >> 23) & 0xff) - 127;
        expo_lds[nxt] = min(max(e, -100), 100);
      }

      mR0  = mR1;  mR1  = mR2;  mR2  = mNew;
      emR0 = emR1; emR1 = emR2; emR2 = emNew;

      asm volatile("s_waitcnt lgkmcnt(0)" ::: "memory");
      __builtin_amdgcn_s_barrier();
      asm volatile("" ::: "memory");
      buf = nxt;
    }

    if (h == 0) qbuf[b * Tc + j] = qi;
    if (tid == 0) meta[4 * b + 3] = (float)Ksum;
  }
}

// Meet: denom_b = M0 + (Kf+Kb)*ln2 + log(p_255 . q_255); partial = score - denom.
__global__ void crf_meet(const float* __restrict__ pbuf,
                         const float* __restrict__ qbuf,
                         const float* __restrict__ meta,
                         float* __restrict__ partial)
{
  const int b = blockIdx.x;
  const int l = threadIdx.x;   // 64
  const float2 pp = *(const float2*)&pbuf[b * Tc + 2 * l];
  const float2 qq = *(const float2*)&qbuf[b * Tc + 2 * l];
  float d = pp.x * qq.x + pp.y * qq.y;
  #pragma unroll
  for (int o = 1; o < 64; o <<= 1) d += __shfl_xor(d, o);
  if (l == 0) {
    const float score = meta[4 * b + 0];
    const float M0    = meta[4 * b + 1];
    const float Ks    = meta[4 * b + 2] + meta[4 * b + 3];
    partial[b] = score - (M0 + Ks * 0.69314718055994531f + __logf(d));
  }
}

// Deterministic final reduction of 256 per-batch llh values -> scalar.
__global__ void crf_reduce(const float* __restrict__ partial, float* __restrict__ out)
{
  const int tid = threadIdx.x;  // 256 threads
  float v = partial[tid];
  #pragma unroll
  for (int o = 1; o < 64; o <<= 1) v += __shfl_xor(v, o);
  __shared__ float ws[4];
  if ((tid & 63) == 0) ws[tid >> 6] = v;
  __syncthreads();
  if (tid == 0) out[0] = (ws[0] + ws[1]) + (ws[2] + ws[3]);
}

extern "C" void kernel_launch(void* const* d_in, const int* in_sizes, int n_in,
                              void* d_out, int out_size, void* d_ws, size_t ws_size,
                              hipStream_t stream)
{
  const float* emis   = (const float*)d_in[0];
  const int*   tags   = (const int*)d_in[1];
  const int*   mask   = (const int*)d_in[2];
  const float* startT = (const float*)d_in[3];
  const float* endT   = (const float*)d_in[4];
  const float* trans  = (const float*)d_in[5];

  float* ws      = (float*)d_ws;
  float* pbuf    = ws;                       // 256*128
  float* qbuf    = ws + 32768;               // 256*128
  float* meta    = ws + 65536;               // 256*4
  float* partial = ws + 66560;               // 256

  crf_llh_kernel<<<2 * Bc, 256, 0, stream>>>(emis, tags, mask, startT, endT,
                                             trans, pbuf, qbuf, meta);
  crf_meet<<<Bc, 64, 0, stream>>>(pbuf, qbuf, meta, partial);
  crf_reduce<<<1, Bc, 0, stream>>>(partial, (float*)d_out);
}